// Round 5
// baseline (35.948 us; speedup 1.0000x reference)
//
#include <hip/hip_runtime.h>
#include <hip/hip_bf16.h>

// Problem constants (from reference): B=32, N=2048, M=16, K=32, H=in_sizes[2]
constexpr int Bc = 32;
constexpr int Nc = 2048;
constexpr int Mc = 16;
constexpr int Kc = 32;
constexpr int KG = 4;              // k values per block
constexpr int ROWc = Mc + 1;       // 17 floats per dgm row
constexpr float EPSc = 1e-7f;

// ---------------------------------------------------------------------------
// Kernel A: one block per (b, k-group of 4), 256 threads, 256 blocks total.
// Per 256-row chunk: float4-stage into LDS -> own row to regs -> block-min
// first-zero row -> accumulate 4 k's:  acc[kk][m] += coef(n,kk) * y[n,m],
// where coef = atanh(xn)/xn * d * w  and  zn2 = sum(y^2 * th^2)  (z never
// materialized; final T multiplies th[k][m] once).
// ---------------------------------------------------------------------------
__global__ __launch_bounds__(256) void k_fused(const float* __restrict__ dgm,
                                               const float* __restrict__ theta,
                                               const float* __restrict__ class_w,
                                               float* __restrict__ T,
                                               int H) {
    __shared__ float lds[256 * ROWc];   // 17408 B
    __shared__ int   wmin[4];
    __shared__ float red[4][Mc];

    int bid = blockIdx.x;
    int b   = bid >> 3;                 // 8 k-groups per batch
    int kg  = bid & 7;
    int tid = threadIdx.x;
    int wid = tid >> 6;

    // th^2 for the 4 k's of this group (th itself only needed at the end)
    float th2[KG][Mc];
#pragma unroll
    for (int kk = 0; kk < KG; ++kk)
#pragma unroll
        for (int m = 0; m < Mc; ++m) {
            float t = theta[(kg * KG + kk) * Mc + m];
            th2[kk][m] = t * t;
        }

    float acc[KG][Mc];
#pragma unroll
    for (int kk = 0; kk < KG; ++kk)
#pragma unroll
        for (int m = 0; m < Mc; ++m) acc[kk][m] = 0.0f;

    const float* base = dgm + (size_t)b * Nc * ROWc;
    int fzb = 0x7FFFFFFF;

    for (int c0 = 0; c0 < Nc; c0 += 256) {
        // ---- stage chunk: 1088 float4 = 256*17 floats, fully coalesced ----
        const float4* src4 = (const float4*)(base + (size_t)c0 * ROWc);
        float4* lds4 = (float4*)lds;
#pragma unroll
        for (int j = 0; j < 4; ++j)
            lds4[tid + j * 256] = src4[tid + j * 256];
        if (tid < 64) lds4[1024 + tid] = src4[1024 + tid];
        __syncthreads();

        // ---- own row (stride-17 -> conflict-light) ----
        float r[ROWc];
#pragma unroll
        for (int j = 0; j < ROWc; ++j) r[j] = lds[tid * ROWc + j];

        // ---- chunk-local first-zero-row reduce ----
        bool nz = false;
#pragma unroll
        for (int j = 0; j < ROWc; ++j) nz = nz || (r[j] != 0.0f);
        int lm = nz ? 0x7FFFFFFF : (c0 + tid);
#pragma unroll
        for (int mask = 32; mask >= 1; mask >>= 1)
            lm = min(lm, __shfl_xor(lm, mask));
        if ((tid & 63) == 0) wmin[wid] = lm;
        __syncthreads();
        fzb = min(fzb, min(min(wmin[0], wmin[1]), min(wmin[2], wmin[3])));

        // ---- accumulate valid rows ----
        int n = c0 + tid;
        if (n < fzb) {
            int h = (int)r[0];              // trunc == astype(int32)
            h = max(0, min(h, H - 1));
            float wv = class_w[h];

            float r2[Mc];
#pragma unroll
            for (int m = 0; m < Mc; ++m) r2[m] = r[1 + m] * r[1 + m];

#pragma unroll
            for (int kk = 0; kk < KG; ++kk) {
                float zn2 = 0.0f;
#pragma unroll
                for (int m = 0; m < Mc; ++m) zn2 = fmaf(r2[m], th2[kk][m], zn2);
                float d   = 1.0f / (1.0f + sqrtf(1.0f + zn2));
                float xn2 = zn2 * d * d;        // ||x||^2 = d^2 ||z||^2
                float xn  = sqrtf(xn2);
                float u   = fminf(xn, 1.0f - EPSc);
                float at  = 0.5f * __logf((1.0f + u) / (1.0f - u));  // atanh
                float coef = at / fmaxf(xn, EPSc) * d * wv;          // 0 if wv==0
#pragma unroll
                for (int m = 0; m < Mc; ++m)
                    acc[kk][m] = fmaf(coef, r[1 + m], acc[kk][m]);
            }
        }

        if (c0 + 256 >= fzb) break;         // all later rows invalid
        __syncthreads();
    }

    // ---- block reduce per kk, then T = th * sum ----
#pragma unroll
    for (int kk = 0; kk < KG; ++kk) {
#pragma unroll
        for (int m = 0; m < Mc; ++m) {
#pragma unroll
            for (int mask = 32; mask >= 1; mask >>= 1)
                acc[kk][m] += __shfl_xor(acc[kk][m], mask);
        }
        __syncthreads();
        if ((tid & 63) == 0) {
#pragma unroll
            for (int m = 0; m < Mc; ++m) red[wid][m] = acc[kk][m];
        }
        __syncthreads();
        if (tid < Mc) {
            int m = tid;
            int k = kg * KG + kk;
            float s = red[0][m] + red[1][m] + red[2][m] + red[3][m];
            T[((size_t)b * Kc + k) * Mc + m] = theta[k * Mc + m] * s;
        }
    }
}

// ---------------------------------------------------------------------------
// Kernel B: S = cumsum over flattened (B*K, M) rows of T, then
//           yd = 2*xd/(1-||xd||^2), xd = tanh(||S||)*S/max(||S||,eps).
// Single block, 1024 threads. thread = (m = tid&15, seg = tid>>4).
// ---------------------------------------------------------------------------
__global__ __launch_bounds__(1024) void k_scan(float* __restrict__ T) {
    __shared__ float buf[2][64][Mc];

    int tid = threadIdx.x;
    int m   = tid & 15;
    int seg = tid >> 4;            // 0..63, 16 rows each -> 1024 rows

    float p[16];
    float run = 0.0f;
#pragma unroll
    for (int j = 0; j < 16; ++j) {
        run += T[(size_t)(seg * 16 + j) * Mc + m];
        p[j] = run;
    }

    buf[0][seg][m] = run;
    __syncthreads();
    int src = 0;
#pragma unroll
    for (int d = 1; d < 64; d <<= 1) {
        float v = buf[src][seg][m];
        if (seg >= d) v += buf[src][seg - d][m];
        buf[src ^ 1][seg][m] = v;
        __syncthreads();
        src ^= 1;
    }
    float off = (seg > 0) ? buf[src][seg - 1][m] : 0.0f;

#pragma unroll
    for (int j = 0; j < 16; ++j) {
        float S = off + p[j];
        float sn2 = S * S;
        sn2 += __shfl_xor(sn2, 1);
        sn2 += __shfl_xor(sn2, 2);
        sn2 += __shfl_xor(sn2, 4);
        sn2 += __shfl_xor(sn2, 8);
        float sn = sqrtf(sn2);
        // tanh(sn) = 1 - 2/(e^{2 sn}+1), exact enough (sn>=0)
        float e  = __expf(2.0f * sn);
        float t  = 1.0f - 2.0f / (e + 1.0f);
        float c  = t / fmaxf(sn, EPSc);
        float sx2 = c * c * sn2;               // == sum(xd^2)
        float yd = 2.0f * c * S / (1.0f - sx2);
        T[(size_t)(seg * 16 + j) * Mc + m] = yd;
    }
}

// ---------------------------------------------------------------------------
extern "C" void kernel_launch(void* const* d_in, const int* in_sizes, int n_in,
                              void* d_out, int out_size, void* d_ws, size_t ws_size,
                              hipStream_t stream) {
    const float* dgm     = (const float*)d_in[0];   // (B, N, 17)
    const float* theta   = (const float*)d_in[1];   // (K, M)
    const float* class_w = (const float*)d_in[2];   // (H,)
    int H = in_sizes[2];

    float* out = (float*)d_out;                     // T, then yd in place

    k_fused<<<Bc * (Kc / KG), 256, 0, stream>>>(dgm, theta, class_w, out, H);
    k_scan<<<1, 1024, 0, stream>>>(out);
}